// Round 2
// baseline (380.121 us; speedup 1.0000x reference)
//
#include <hip/hip_runtime.h>
#include <hip/hip_bf16.h>

// ---------------------------------------------------------------------------
// Spiking Swin block: QKV(+LIF) -> binary attention (+rpb) -> PV -> proj(+LIF)
// I/O dtype: FLOAT32 (reference is f32; round-1 NaN proved f32 output layout).
// f32 operands converted to bf16 during LDS staging for MFMA 16x16x32 compute.
// Spikes (exact 0/1) stored as bf16 in workspace. attn written in pure f32
// (cnt*SCALE + rpb) -> exact vs reference when no spikes fire.
//
// Index facts (literal row-major reshapes):
//  - q.reshape(256,4,256,32) is identity on the flat (t,b,h,w,c) buffer:
//    (b_new,head) tile = 8192 contiguous elems at (b_new*4+head)*8192.
//  - out0 flat = t2*2097152 + b*8192 + hw*128 + d   (f32)
//  - attn flat = ((b*4+head)*256 + n)*256 + m       (f32)
// ---------------------------------------------------------------------------

typedef __attribute__((ext_vector_type(8))) short bf16x8;   // 8 bf16 = 4 VGPRs
typedef __attribute__((ext_vector_type(4))) float f32x4;

#define MFMA16(a, b, c) __builtin_amdgcn_mfma_f32_16x16x32_bf16((a), (b), (c), 0, 0, 0)

__device__ __forceinline__ unsigned short f2bf(float f) {
    union { __hip_bfloat16 h; unsigned short u; } cv;
    cv.h = __float2bfloat16(f);                      // RNE
    return cv.u;
}
__device__ __forceinline__ float bf2f(unsigned short u) {
    union { unsigned int i; float f; } cv;
    cv.i = ((unsigned int)u) << 16;                  // exact upcast
    return cv.f;
}

// Convert 8 consecutive f32 -> 8 bf16 and store 16B to LDS.
__device__ __forceinline__ void cvt8_store(unsigned short* dst, const float* src) {
    float4 f0 = *(const float4*)(src);
    float4 f1 = *(const float4*)(src + 4);
    unsigned short h[8];
    h[0] = f2bf(f0.x); h[1] = f2bf(f0.y); h[2] = f2bf(f0.z); h[3] = f2bf(f0.w);
    h[4] = f2bf(f1.x); h[5] = f2bf(f1.y); h[6] = f2bf(f1.z); h[7] = f2bf(f1.w);
    *(uint4*)dst = *(const uint4*)h;
}

// ---------------------------------------------------------------------------
// Kernel D: expand rpb_table (1575,4) f32 -> rpbx[head][n][m] (4,256,256) f32
// ---------------------------------------------------------------------------
__global__ __launch_bounds__(256) void k_rpb_expand(
    const float* __restrict__ tbl, float* __restrict__ rpbx)
{
    int idx = blockIdx.x * 256 + threadIdx.x;        // 262144 total
    int hh = idx >> 16;
    int n = (idx >> 8) & 255, m = idx & 255;
    int zn = n >> 6, yn = (n >> 3) & 7, xn = n & 7;
    int zm = m >> 6, ym = (m >> 3) & 7, xm = m & 7;
    int ri = (zn - zm + 3) * 225 + (yn - ym + 7) * 15 + (xn - xm + 7);
    rpbx[idx] = tbl[ri * 4 + hh];
}

// ---------------------------------------------------------------------------
// Kernel A: per weight (blockIdx.y in {q,k,v}) GEMM X@W^T (MFMA) + LIF over t.
// Block = 64 rows x 128 cols, grid.x = 256 row-tiles. Spikes (bf16 0/1) -> ws.
// ---------------------------------------------------------------------------
__global__ __launch_bounds__(256) void k_qkv_lif(
    const float* __restrict__ x,
    const float* __restrict__ Wq,
    const float* __restrict__ Wk,
    const float* __restrict__ Wv,
    unsigned short* __restrict__ q_ws,
    unsigned short* __restrict__ k_ws,
    unsigned short* __restrict__ v_ws)
{
    __shared__ unsigned short Wl[128 * 136];   // W rows d (N) x cols c (K), pad +8
    __shared__ unsigned short Xl[64 * 136];    // X rows r (M) x cols c (K), pad +8

    const int tid = threadIdx.x;
    const int wv = tid >> 6, lane = tid & 63;
    const int l15 = lane & 15, lh = lane >> 4;
    const int wsel = blockIdx.y;
    const float* W = (wsel == 0) ? Wq : (wsel == 1) ? Wk : Wv;
    unsigned short* outp = (wsel == 0) ? q_ws : (wsel == 1) ? k_ws : v_ws;
    const int rowbase = blockIdx.x * 64;

    {   // stage W (128x128 f32 -> bf16)
#pragma unroll
        for (int i = 0; i < 8; ++i) {
            int e = i * 2048 + tid * 8;
            int r = e >> 7, cc = e & 127;
            cvt8_store(&Wl[r * 136 + cc], W + r * 128 + cc);
        }
    }

    f32x4 vst[8];                                   // LIF membrane, persists over t
#pragma unroll
    for (int nt = 0; nt < 8; ++nt) vst[nt] = (f32x4){0.f, 0.f, 0.f, 0.f};

    for (int t = 0; t < 4; ++t) {
        __syncthreads();                            // Xl reuse / Wl ready
        const float* xg = x + t * 2097152 + rowbase * 128;
#pragma unroll
        for (int i = 0; i < 4; ++i) {
            int e = i * 2048 + tid * 8;
            int r = e >> 7, cc = e & 127;
            cvt8_store(&Xl[r * 136 + cc], xg + r * 128 + cc);
        }
        __syncthreads();

        f32x4 acc[8];
#pragma unroll
        for (int nt = 0; nt < 8; ++nt) acc[nt] = (f32x4){0.f, 0.f, 0.f, 0.f};
#pragma unroll
        for (int kk = 0; kk < 4; ++kk) {
            bf16x8 a = *(const bf16x8*)&Xl[(wv * 16 + l15) * 136 + kk * 32 + lh * 8];
#pragma unroll
            for (int nt = 0; nt < 8; ++nt) {
                bf16x8 b = *(const bf16x8*)&Wl[(nt * 16 + l15) * 136 + kk * 32 + lh * 8];
                acc[nt] = MFMA16(a, b, acc[nt]);
            }
        }
        // LIF epilogue: v += (y-v)/2; s=(v>=1); v*=(1-s); store spike bf16
        unsigned short* og = outp + t * 2097152;
#pragma unroll
        for (int nt = 0; nt < 8; ++nt) {
#pragma unroll
            for (int reg = 0; reg < 4; ++reg) {
                float y = acc[nt][reg];
                float v = vst[nt][reg];
                v = v + (y - v) * 0.5f;
                float s = (v >= 1.0f) ? 1.0f : 0.0f;
                vst[nt][reg] = v * (1.0f - s);
                int r = rowbase + wv * 16 + lh * 4 + reg;
                og[r * 128 + nt * 16 + l15] =
                    (s != 0.0f) ? (unsigned short)0x3F80 : (unsigned short)0;
            }
        }
    }
}

// ---------------------------------------------------------------------------
// Kernel B: one block per (b_new, head). attn row via popcount of packed
// spike bits + rpb (f32, exact), write f32 to out + bf16 to LDS; then
// o = attn@v via MFMA -> o_ws (bf16).
// ---------------------------------------------------------------------------
__global__ __launch_bounds__(256) void k_attn(
    const unsigned short* __restrict__ q_ws,
    const unsigned short* __restrict__ k_ws,
    const unsigned short* __restrict__ v_ws,
    const float* __restrict__ rpbx,
    float* __restrict__ attn_out,
    unsigned short* __restrict__ o_ws)
{
    __shared__ unsigned int  qb[256];          // q row bitmasks
    __shared__ unsigned short vT[32 * 264];    // v transposed: [hd][m], pad +8
    __shared__ unsigned short attnL[64 * 264]; // attn chunk: [n_loc][m], pad +8

    const int tid = threadIdx.x;
    const int wv = tid >> 6, lane = tid & 63;
    const int l15 = lane & 15, lh = lane >> 4;
    const int hh = blockIdx.x & 3;
    const int base = blockIdx.x * 8192;        // (b*4+hh)*256*32

    {   // q bitmask -> LDS
        const unsigned short* qr = q_ws + base + tid * 32;
        unsigned int m = 0;
#pragma unroll
        for (int j = 0; j < 32; j += 8) {
            uint4 u = *(const uint4*)(qr + j);
            if (u.x & 0xFFFFu) m |= 1u << (j + 0);
            if (u.x >> 16)     m |= 1u << (j + 1);
            if (u.y & 0xFFFFu) m |= 1u << (j + 2);
            if (u.y >> 16)     m |= 1u << (j + 3);
            if (u.z & 0xFFFFu) m |= 1u << (j + 4);
            if (u.z >> 16)     m |= 1u << (j + 5);
            if (u.w & 0xFFFFu) m |= 1u << (j + 6);
            if (u.w >> 16)     m |= 1u << (j + 7);
        }
        qb[tid] = m;
    }
    unsigned int km = 0;
    {   // k bitmask -> register (thread owns column m = tid)
        const unsigned short* kr = k_ws + base + tid * 32;
#pragma unroll
        for (int j = 0; j < 32; j += 8) {
            uint4 u = *(const uint4*)(kr + j);
            if (u.x & 0xFFFFu) km |= 1u << (j + 0);
            if (u.x >> 16)     km |= 1u << (j + 1);
            if (u.y & 0xFFFFu) km |= 1u << (j + 2);
            if (u.y >> 16)     km |= 1u << (j + 3);
            if (u.z & 0xFFFFu) km |= 1u << (j + 4);
            if (u.z >> 16)     km |= 1u << (j + 5);
            if (u.w & 0xFFFFu) km |= 1u << (j + 6);
            if (u.w >> 16)     km |= 1u << (j + 7);
        }
    }
    {   // v -> LDS transposed vT[hd][m]
        const unsigned short* vr = v_ws + base + tid * 32;
#pragma unroll
        for (int j = 0; j < 32; j += 8) {
            uint4 u = *(const uint4*)(vr + j);
            vT[(j + 0) * 264 + tid] = (unsigned short)(u.x & 0xFFFFu);
            vT[(j + 1) * 264 + tid] = (unsigned short)(u.x >> 16);
            vT[(j + 2) * 264 + tid] = (unsigned short)(u.y & 0xFFFFu);
            vT[(j + 3) * 264 + tid] = (unsigned short)(u.y >> 16);
            vT[(j + 4) * 264 + tid] = (unsigned short)(u.z & 0xFFFFu);
            vT[(j + 5) * 264 + tid] = (unsigned short)(u.z >> 16);
            vT[(j + 6) * 264 + tid] = (unsigned short)(u.w & 0xFFFFu);
            vT[(j + 7) * 264 + tid] = (unsigned short)(u.w >> 16);
        }
    }
    __syncthreads();

    const float SC = 0.17677669529663687f;     // 32^-0.5
    float* attn_b = attn_out + (size_t)blockIdx.x * 65536;
    const float* rp = rpbx + hh * 65536;
    unsigned short* ob = o_ws + base;

    for (int c = 0; c < 4; ++c) {
        // attn rows n = c*64 + j; thread owns column m = tid
        for (int j = 0; j < 64; ++j) {
            int n = c * 64 + j;
            unsigned int qn = qb[n];
            int cnt = __popc(qn & km);
            float av = (float)cnt * SC + rp[n * 256 + tid];
            attnL[j * 264 + tid] = f2bf(av);
            attn_b[n * 256 + tid] = av;        // exact f32 output
        }
        __syncthreads();
        // o(64x32) = attnL(64x256) @ v(256x32); wave owns 16 rows
        f32x4 oc[2];
        oc[0] = (f32x4){0.f, 0.f, 0.f, 0.f};
        oc[1] = (f32x4){0.f, 0.f, 0.f, 0.f};
#pragma unroll
        for (int kk = 0; kk < 8; ++kk) {
            bf16x8 a = *(const bf16x8*)&attnL[(wv * 16 + l15) * 264 + kk * 32 + lh * 8];
#pragma unroll
            for (int nt = 0; nt < 2; ++nt) {
                bf16x8 b = *(const bf16x8*)&vT[(nt * 16 + l15) * 264 + kk * 32 + lh * 8];
                oc[nt] = MFMA16(a, b, oc[nt]);
            }
        }
#pragma unroll
        for (int nt = 0; nt < 2; ++nt) {
#pragma unroll
            for (int reg = 0; reg < 4; ++reg) {
                int n = c * 64 + wv * 16 + lh * 4 + reg;
                ob[n * 32 + nt * 16 + l15] = f2bf(oc[nt][reg]);
            }
        }
        __syncthreads();                        // attnL reuse next chunk
    }
}

// ---------------------------------------------------------------------------
// Kernel C: per b_new: gather o across heads -> A(256x128); Y = A@Wp^T + bias;
// LIF over t2 (rows n = t2*64 + hw). Chunked by hw (4 chunks of 16) so each
// wave holds all 4 timesteps of its elements in accumulators.
// ---------------------------------------------------------------------------
__global__ __launch_bounds__(256) void k_proj_lif(
    const unsigned short* __restrict__ o_ws,
    const float* __restrict__ Wp,
    const float* __restrict__ bp,
    float* __restrict__ out0)
{
    __shared__ unsigned short Wl[128 * 136];
    __shared__ unsigned short Al[64 * 136];

    const int tid = threadIdx.x;
    const int wv = tid >> 6, lane = tid & 63;
    const int l15 = lane & 15, lh = lane >> 4;
    const int b = blockIdx.x;

    {   // stage Wproj (f32 -> bf16)
#pragma unroll
        for (int i = 0; i < 8; ++i) {
            int e = i * 2048 + tid * 8;
            int r = e >> 7, cc = e & 127;
            cvt8_store(&Wl[r * 136 + cc], Wp + r * 128 + cc);
        }
    }

    float biasf[2];
#pragma unroll
    for (int ntl = 0; ntl < 2; ++ntl)
        biasf[ntl] = bp[(wv * 2 + ntl) * 16 + l15];

    const unsigned short* ob = o_ws + b * 32768;   // o[b][head][n][hd] bf16

    for (int c = 0; c < 4; ++c) {                  // hw group c*16 .. c*16+15
        __syncthreads();
        // Al rows lr2 = t2*16+rit, cols cc = head*32+hd; n = t2*64 + c*16 + rit
#pragma unroll
        for (int i = 0; i < 4; ++i) {
            int e = i * 2048 + tid * 8;
            int lr2 = e >> 7, cc = e & 127;
            int t2 = lr2 >> 4, rit = lr2 & 15;
            int hhh = cc >> 5, hd = cc & 31;
            int n = t2 * 64 + c * 16 + rit;
            *(uint4*)&Al[lr2 * 136 + cc] =
                *(const uint4*)(ob + (hhh * 256 + n) * 32 + hd);
        }
        __syncthreads();

        f32x4 acc[4][2];
#pragma unroll
        for (int t2 = 0; t2 < 4; ++t2)
#pragma unroll
            for (int ntl = 0; ntl < 2; ++ntl)
                acc[t2][ntl] = (f32x4){0.f, 0.f, 0.f, 0.f};
#pragma unroll
        for (int kk = 0; kk < 4; ++kk) {
            bf16x8 a[4];
#pragma unroll
            for (int t2 = 0; t2 < 4; ++t2)
                a[t2] = *(const bf16x8*)&Al[(t2 * 16 + l15) * 136 + kk * 32 + lh * 8];
#pragma unroll
            for (int ntl = 0; ntl < 2; ++ntl) {
                bf16x8 bb = *(const bf16x8*)&Wl[((wv * 2 + ntl) * 16 + l15) * 136 + kk * 32 + lh * 8];
#pragma unroll
                for (int t2 = 0; t2 < 4; ++t2)
                    acc[t2][ntl] = MFMA16(a[t2], bb, acc[t2][ntl]);
            }
        }
        // bias + LIF over t2, store spikes (f32 0/1)
#pragma unroll
        for (int ntl = 0; ntl < 2; ++ntl) {
            int d = (wv * 2 + ntl) * 16 + l15;
#pragma unroll
            for (int reg = 0; reg < 4; ++reg) {
                int hw = c * 16 + lh * 4 + reg;
                float v = 0.f;
#pragma unroll
                for (int t2 = 0; t2 < 4; ++t2) {
                    float y = acc[t2][ntl][reg] + biasf[ntl];
                    v = v + (y - v) * 0.5f;
                    float s = (v >= 1.0f) ? 1.0f : 0.0f;
                    v = v * (1.0f - s);
                    out0[t2 * 2097152 + b * 8192 + hw * 128 + d] = s;
                }
            }
        }
    }
}

// ---------------------------------------------------------------------------
extern "C" void kernel_launch(void* const* d_in, const int* in_sizes, int n_in,
                              void* d_out, int out_size, void* d_ws, size_t ws_size,
                              hipStream_t stream)
{
    const float* x   = (const float*)d_in[0];
    const float* Wq  = (const float*)d_in[1];
    const float* Wk  = (const float*)d_in[2];
    const float* Wv  = (const float*)d_in[3];
    const float* tbl = (const float*)d_in[4];
    const float* Wp  = (const float*)d_in[5];
    const float* bp  = (const float*)d_in[6];

    float* out0 = (float*)d_out;                                // 8388608 f32
    float* attn = out0 + 8388608;                               // 67108864 f32

    unsigned short* q_ws = (unsigned short*)d_ws;               // bf16 spikes
    unsigned short* k_ws = q_ws + 8388608;
    unsigned short* v_ws = k_ws + 8388608;
    unsigned short* o_ws = v_ws + 8388608;
    float* rpbx = (float*)(o_ws + 8388608);                     // 262144 f32
    // total ws use: 4*16.78MB + 1.05MB ≈ 68.2 MB

    k_rpb_expand<<<1024, 256, 0, stream>>>(tbl, rpbx);
    k_qkv_lif<<<dim3(256, 3), 256, 0, stream>>>(x, Wq, Wk, Wv, q_ws, k_ws, v_ws);
    k_attn<<<1024, 256, 0, stream>>>(q_ws, k_ws, v_ws, rpbx, attn, o_ws);
    k_proj_lif<<<256, 256, 0, stream>>>(o_ws, Wp, bp, out0);
}

// Round 3
// 354.257 us; speedup vs baseline: 1.0730x; 1.0730x over previous
//
#include <hip/hip_runtime.h>
#include <hip/hip_bf16.h>

// ---------------------------------------------------------------------------
// Spiking Swin block: QKV(+LIF) -> binary attention (+rpb) -> PV -> proj(+LIF)
// I/O: float32. MFMA bf16 16x16x32 for GEMM work (exact for 0/1 spikes).
//
// Index facts (flat-order-preserving reshapes, verified by R2 absmax=0.0):
//  - attention group g = flat>>13 over the (t,b,hw,c) buffer; each kernel-A
//    block (B,t) covers exactly group g = t*256 + B, with n = hw*4 + (c>>5),
//    d = c&31. So one block produces one group's full 256x32 spike tile.
//  - q/k/v spikes are binary -> stored as bit-packed uint32[g][n] over d.
//  - attn flat = (g*256 + n)*256 + m   (f32 output)
//  - out0 flat = t2*2097152 + b*8192 + hw*128 + c  (f32 output)
// ---------------------------------------------------------------------------

typedef __attribute__((ext_vector_type(8))) short bf16x8;   // 8 bf16 = 4 VGPRs
typedef __attribute__((ext_vector_type(4))) float f32x4;

#define MFMA16(a, b, c) __builtin_amdgcn_mfma_f32_16x16x32_bf16((a), (b), (c), 0, 0, 0)

__device__ __forceinline__ unsigned short f2bf(float f) {
    union { __hip_bfloat16 h; unsigned short u; } cv;
    cv.h = __float2bfloat16(f);                      // RNE
    return cv.u;
}

// Convert 8 consecutive f32 -> 8 bf16 and store 16B to LDS.
__device__ __forceinline__ void cvt8_store(unsigned short* dst, const float* src) {
    float4 f0 = *(const float4*)(src);
    float4 f1 = *(const float4*)(src + 4);
    unsigned short h[8];
    h[0] = f2bf(f0.x); h[1] = f2bf(f0.y); h[2] = f2bf(f0.z); h[3] = f2bf(f0.w);
    h[4] = f2bf(f1.x); h[5] = f2bf(f1.y); h[6] = f2bf(f1.z); h[7] = f2bf(f1.w);
    *(uint4*)dst = *(const uint4*)h;
}

// ---------------------------------------------------------------------------
// Kernel D: expand rpb_table (1575,4) f32 -> rpbx[head][n][m] (4,256,256) f32
// ---------------------------------------------------------------------------
__global__ __launch_bounds__(256) void k_rpb_expand(
    const float* __restrict__ tbl, float* __restrict__ rpbx)
{
    int idx = blockIdx.x * 256 + threadIdx.x;        // 262144 total
    int hh = idx >> 16;
    int n = (idx >> 8) & 255, m = idx & 255;
    int zn = n >> 6, yn = (n >> 3) & 7, xn = n & 7;
    int zm = m >> 6, ym = (m >> 3) & 7, xm = m & 7;
    int ri = (zn - zm + 3) * 225 + (yn - ym + 7) * 15 + (xn - xm + 7);
    rpbx[idx] = tbl[ri * 4 + hh];
}

// ---------------------------------------------------------------------------
// Kernel A: per weight (blockIdx.y in {q,k,v}) GEMM X@W^T (MFMA) + LIF over t.
// Block = 64 rows x 128 cols = one attention group (t*256+B) per t iteration.
// Output: bit-packed spikes, 1 uint32 per (g,n), bits over d=0..31.
// ---------------------------------------------------------------------------
__global__ __launch_bounds__(256) void k_qkv_lif(
    const float* __restrict__ x,
    const float* __restrict__ Wq,
    const float* __restrict__ Wk,
    const float* __restrict__ Wv,
    unsigned int* __restrict__ qbits,
    unsigned int* __restrict__ kbits,
    unsigned int* __restrict__ vbits)
{
    __shared__ unsigned short Wl[128 * 136];   // W rows d (N) x cols c (K), pad +8
    __shared__ unsigned short Xl[64 * 136];    // X tile / spike tile (reused)

    const int tid = threadIdx.x;
    const int wv = tid >> 6, lane = tid & 63;
    const int l15 = lane & 15, lh = lane >> 4;
    const int wsel = blockIdx.y;
    const float* W = (wsel == 0) ? Wq : (wsel == 1) ? Wk : Wv;
    unsigned int* bits = (wsel == 0) ? qbits : (wsel == 1) ? kbits : vbits;
    const int B = blockIdx.x;

    {   // stage W (128x128 f32 -> bf16)
#pragma unroll
        for (int i = 0; i < 8; ++i) {
            int e = i * 2048 + tid * 8;
            int r = e >> 7, cc = e & 127;
            cvt8_store(&Wl[r * 136 + cc], W + r * 128 + cc);
        }
    }

    f32x4 vst[8];                                   // LIF membrane, persists over t
#pragma unroll
    for (int nt = 0; nt < 8; ++nt) vst[nt] = (f32x4){0.f, 0.f, 0.f, 0.f};

    for (int t = 0; t < 4; ++t) {
        __syncthreads();                            // Xl free (pack reads done)
        const float* xg = x + t * 2097152 + B * 8192;
#pragma unroll
        for (int i = 0; i < 4; ++i) {
            int e = i * 2048 + tid * 8;
            int r = e >> 7, cc = e & 127;
            cvt8_store(&Xl[r * 136 + cc], xg + r * 128 + cc);
        }
        __syncthreads();

        f32x4 acc[8];
#pragma unroll
        for (int nt = 0; nt < 8; ++nt) acc[nt] = (f32x4){0.f, 0.f, 0.f, 0.f};
#pragma unroll
        for (int kk = 0; kk < 4; ++kk) {
            bf16x8 a = *(const bf16x8*)&Xl[(wv * 16 + l15) * 136 + kk * 32 + lh * 8];
#pragma unroll
            for (int nt = 0; nt < 8; ++nt) {
                bf16x8 b = *(const bf16x8*)&Wl[(nt * 16 + l15) * 136 + kk * 32 + lh * 8];
                acc[nt] = MFMA16(a, b, acc[nt]);
            }
        }
        // LIF: v += (y-v)/2; s=(v>=1); v*=(1-s); spike shorts -> Xl
        unsigned short sp[8][4];
#pragma unroll
        for (int nt = 0; nt < 8; ++nt) {
#pragma unroll
            for (int reg = 0; reg < 4; ++reg) {
                float y = acc[nt][reg];
                float v = vst[nt][reg];
                v = v + (y - v) * 0.5f;
                float s = (v >= 1.0f) ? 1.0f : 0.0f;
                vst[nt][reg] = v * (1.0f - s);
                sp[nt][reg] = (s != 0.0f) ? (unsigned short)1 : (unsigned short)0;
            }
        }
        __syncthreads();                            // all MFMA reads of Xl done
#pragma unroll
        for (int nt = 0; nt < 8; ++nt)
#pragma unroll
            for (int reg = 0; reg < 4; ++reg)
                Xl[(wv * 16 + lh * 4 + reg) * 136 + nt * 16 + l15] = sp[nt][reg];
        __syncthreads();
        // pack: thread u owns n=u: row hw=u>>2, cols (u&3)*32 .. +31 -> 32 bits
        {
            const unsigned short* rowp = &Xl[(tid >> 2) * 136 + (tid & 3) * 32];
            unsigned int mask = 0;
#pragma unroll
            for (int j8 = 0; j8 < 4; ++j8) {
                uint4 u = *(const uint4*)(rowp + j8 * 8);
                int base = j8 * 8;
                if (u.x & 0xFFFFu) mask |= 1u << (base + 0);
                if (u.x >> 16)     mask |= 1u << (base + 1);
                if (u.y & 0xFFFFu) mask |= 1u << (base + 2);
                if (u.y >> 16)     mask |= 1u << (base + 3);
                if (u.z & 0xFFFFu) mask |= 1u << (base + 4);
                if (u.z >> 16)     mask |= 1u << (base + 5);
                if (u.w & 0xFFFFu) mask |= 1u << (base + 6);
                if (u.w >> 16)     mask |= 1u << (base + 7);
            }
            bits[(t * 256 + B) * 256 + tid] = mask;  // coalesced 1KB
        }
    }
}

// ---------------------------------------------------------------------------
// Kernel B: one block per group g=(b,head). attn[n][m] = popc(q&k)*SC + rpb,
// float4 nontemporal stores (thread owns 4 consecutive m); bf16 copy in LDS;
// then o = attn@v via MFMA (v rebuilt from bits in LDS) -> o_ws (bf16).
// ---------------------------------------------------------------------------
__global__ __launch_bounds__(256) void k_attn(
    const unsigned int* __restrict__ qbits,
    const unsigned int* __restrict__ kbits,
    const unsigned int* __restrict__ vbits,
    const float* __restrict__ rpbx,
    float* __restrict__ attn_out,
    unsigned short* __restrict__ o_ws)
{
    __shared__ unsigned int  qb[256];          // q row bitmasks
    __shared__ unsigned short vT[32 * 264];    // v transposed: [d][n], pad +8
    __shared__ unsigned short attnL[64 * 264]; // attn chunk bf16: [n_loc][m]

    const int tid = threadIdx.x;
    const int wv = tid >> 6, lane = tid & 63;
    const int l15 = lane & 15, lh = lane >> 4;
    const int g = blockIdx.x, hh = g & 3;

    qb[tid] = qbits[g * 256 + tid];
    uint4 km = *(const uint4*)&kbits[g * 256 + (tid & 63) * 4];
    {   // v bits -> bf16 vT[d][n]
        unsigned int vb = vbits[g * 256 + tid];
#pragma unroll
        for (int d = 0; d < 32; ++d)
            vT[d * 264 + tid] = ((vb >> d) & 1u) ? (unsigned short)0x3F80
                                                 : (unsigned short)0;
    }
    __syncthreads();

    const float SC = 0.17677669529663687f;     // 32^-0.5
    float* attn_b = attn_out + (size_t)g * 65536;
    const float* rp = rpbx + hh * 65536;
    unsigned short* ob = o_ws + g * 8192;
    const int rg = tid >> 6, m0 = (tid & 63) * 4;

    for (int c = 0; c < 4; ++c) {
        // rows n = c*64 + j*4 + rg; thread owns cols m0..m0+3
#pragma unroll
        for (int j = 0; j < 16; ++j) {
            int n = c * 64 + j * 4 + rg;
            unsigned int qn = qb[n];
            float4 rp4 = *(const float4*)&rp[n * 256 + m0];
            f32x4 av;
            av.x = (float)__popc(qn & km.x) * SC + rp4.x;
            av.y = (float)__popc(qn & km.y) * SC + rp4.y;
            av.z = (float)__popc(qn & km.z) * SC + rp4.z;
            av.w = (float)__popc(qn & km.w) * SC + rp4.w;
            __builtin_nontemporal_store(av, (f32x4*)(attn_b + n * 256 + m0));
            unsigned int p0 = (unsigned int)f2bf(av.x) | ((unsigned int)f2bf(av.y) << 16);
            unsigned int p1 = (unsigned int)f2bf(av.z) | ((unsigned int)f2bf(av.w) << 16);
            uint2 pk; pk.x = p0; pk.y = p1;
            *(uint2*)&attnL[(j * 4 + rg) * 264 + m0] = pk;
        }
        __syncthreads();
        // o(64x32) = attnL(64x256) @ v(256x32); wave owns 16 rows
        f32x4 oc[2];
        oc[0] = (f32x4){0.f, 0.f, 0.f, 0.f};
        oc[1] = (f32x4){0.f, 0.f, 0.f, 0.f};
#pragma unroll
        for (int kk = 0; kk < 8; ++kk) {
            bf16x8 a = *(const bf16x8*)&attnL[(wv * 16 + l15) * 264 + kk * 32 + lh * 8];
#pragma unroll
            for (int nt = 0; nt < 2; ++nt) {
                bf16x8 b = *(const bf16x8*)&vT[(nt * 16 + l15) * 264 + kk * 32 + lh * 8];
                oc[nt] = MFMA16(a, b, oc[nt]);
            }
        }
#pragma unroll
        for (int nt = 0; nt < 2; ++nt) {
#pragma unroll
            for (int reg = 0; reg < 4; ++reg) {
                int n = c * 64 + wv * 16 + lh * 4 + reg;
                ob[n * 32 + nt * 16 + l15] = f2bf(oc[nt][reg]);
            }
        }
        __syncthreads();                        // attnL reuse next chunk
    }
}

// ---------------------------------------------------------------------------
// Kernel C: per b_new: gather o across heads -> A(256x128); Y = A@Wp^T + bias;
// LIF over t2 (rows n = t2*64 + hw). Chunked by hw (4 chunks of 16) so each
// wave holds all 4 timesteps of its elements in accumulators.
// ---------------------------------------------------------------------------
__global__ __launch_bounds__(256) void k_proj_lif(
    const unsigned short* __restrict__ o_ws,
    const float* __restrict__ Wp,
    const float* __restrict__ bp,
    float* __restrict__ out0)
{
    __shared__ unsigned short Wl[128 * 136];
    __shared__ unsigned short Al[64 * 136];

    const int tid = threadIdx.x;
    const int wv = tid >> 6, lane = tid & 63;
    const int l15 = lane & 15, lh = lane >> 4;
    const int b = blockIdx.x;

    {   // stage Wproj (f32 -> bf16)
#pragma unroll
        for (int i = 0; i < 8; ++i) {
            int e = i * 2048 + tid * 8;
            int r = e >> 7, cc = e & 127;
            cvt8_store(&Wl[r * 136 + cc], Wp + r * 128 + cc);
        }
    }

    float biasf[2];
#pragma unroll
    for (int ntl = 0; ntl < 2; ++ntl)
        biasf[ntl] = bp[(wv * 2 + ntl) * 16 + l15];

    const unsigned short* ob = o_ws + b * 32768;   // o[b][head][n][hd] bf16

    for (int c = 0; c < 4; ++c) {                  // hw group c*16 .. c*16+15
        __syncthreads();
        // Al rows lr2 = t2*16+rit, cols cc = head*32+hd; n = t2*64 + c*16 + rit
#pragma unroll
        for (int i = 0; i < 4; ++i) {
            int e = i * 2048 + tid * 8;
            int lr2 = e >> 7, cc = e & 127;
            int t2 = lr2 >> 4, rit = lr2 & 15;
            int hhh = cc >> 5, hd = cc & 31;
            int n = t2 * 64 + c * 16 + rit;
            *(uint4*)&Al[lr2 * 136 + cc] =
                *(const uint4*)(ob + (hhh * 256 + n) * 32 + hd);
        }
        __syncthreads();

        f32x4 acc[4][2];
#pragma unroll
        for (int t2 = 0; t2 < 4; ++t2)
#pragma unroll
            for (int ntl = 0; ntl < 2; ++ntl)
                acc[t2][ntl] = (f32x4){0.f, 0.f, 0.f, 0.f};
#pragma unroll
        for (int kk = 0; kk < 4; ++kk) {
            bf16x8 a[4];
#pragma unroll
            for (int t2 = 0; t2 < 4; ++t2)
                a[t2] = *(const bf16x8*)&Al[(t2 * 16 + l15) * 136 + kk * 32 + lh * 8];
#pragma unroll
            for (int ntl = 0; ntl < 2; ++ntl) {
                bf16x8 bb = *(const bf16x8*)&Wl[((wv * 2 + ntl) * 16 + l15) * 136 + kk * 32 + lh * 8];
#pragma unroll
                for (int t2 = 0; t2 < 4; ++t2)
                    acc[t2][ntl] = MFMA16(a[t2], bb, acc[t2][ntl]);
            }
        }
        // bias + LIF over t2, store spikes (f32 0/1)
#pragma unroll
        for (int ntl = 0; ntl < 2; ++ntl) {
            int d = (wv * 2 + ntl) * 16 + l15;
#pragma unroll
            for (int reg = 0; reg < 4; ++reg) {
                int hw = c * 16 + lh * 4 + reg;
                float v = 0.f;
#pragma unroll
                for (int t2 = 0; t2 < 4; ++t2) {
                    float y = acc[t2][ntl][reg] + biasf[ntl];
                    v = v + (y - v) * 0.5f;
                    float s = (v >= 1.0f) ? 1.0f : 0.0f;
                    v = v * (1.0f - s);
                    out0[t2 * 2097152 + b * 8192 + hw * 128 + d] = s;
                }
            }
        }
    }
}

// ---------------------------------------------------------------------------
extern "C" void kernel_launch(void* const* d_in, const int* in_sizes, int n_in,
                              void* d_out, int out_size, void* d_ws, size_t ws_size,
                              hipStream_t stream)
{
    const float* x   = (const float*)d_in[0];
    const float* Wq  = (const float*)d_in[1];
    const float* Wk  = (const float*)d_in[2];
    const float* Wv  = (const float*)d_in[3];
    const float* tbl = (const float*)d_in[4];
    const float* Wp  = (const float*)d_in[5];
    const float* bp  = (const float*)d_in[6];

    float* out0 = (float*)d_out;                                // 8388608 f32
    float* attn = out0 + 8388608;                               // 67108864 f32

    unsigned short* o_ws = (unsigned short*)d_ws;               // 8388608 bf16
    unsigned int* qbits = (unsigned int*)(o_ws + 8388608);      // 262144 u32
    unsigned int* kbits = qbits + 262144;
    unsigned int* vbits = kbits + 262144;
    float* rpbx = (float*)(vbits + 262144);                     // 262144 f32
    // total ws use: ~21 MB

    k_rpb_expand<<<1024, 256, 0, stream>>>(tbl, rpbx);
    k_qkv_lif<<<dim3(256, 3), 256, 0, stream>>>(x, Wq, Wk, Wv, qbits, kbits, vbits);
    k_attn<<<1024, 256, 0, stream>>>(qbits, kbits, vbits, rpbx, attn, o_ws);
    k_proj_lif<<<256, 256, 0, stream>>>(o_ws, Wp, bp, out0);
}

// Round 5
// 352.654 us; speedup vs baseline: 1.0779x; 1.0045x over previous
//
#include <hip/hip_runtime.h>
#include <hip/hip_bf16.h>

// ---------------------------------------------------------------------------
// Spiking Swin block: QKV(+LIF) -> binary attention (+rpb) -> PV -> proj(+LIF)
// I/O: float32. MFMA bf16 16x16x32 for GEMM work (exact for 0/1 spikes).
//
// Index facts (flat-order-preserving reshapes, verified by R2/R3 absmax=0.0):
//  - attention group g = flat>>13 over the (t,b,hw,c) buffer; kernel-A block
//    (B,t) covers exactly group g = t*256 + B, with n = hw*4 + (c>>5), d=c&31.
//  - q/k/v spikes are binary -> bit-packed uint32[g][n] over d.
//  - attn flat = (g*256 + n)*256 + m   (f32 output)
//  - out0 flat = t2*2097152 + b*8192 + hw*128 + c  (f32 output)
//
// R3 lesson: timed window includes ~245 us of harness poison fills; our
// controllable share is ~110 us. This round (resubmit of R4 after infra
// failure): fold rpb kernel into k_qkv grid, k_attn 32-row chunks (LDS
// 34.8 KB -> 4 blocks/CU), nontemporal out stores.
// ---------------------------------------------------------------------------

typedef __attribute__((ext_vector_type(8))) short bf16x8;   // 8 bf16 = 4 VGPRs
typedef __attribute__((ext_vector_type(4))) float f32x4;

#define MFMA16(a, b, c) __builtin_amdgcn_mfma_f32_16x16x32_bf16((a), (b), (c), 0, 0, 0)

__device__ __forceinline__ unsigned short f2bf(float f) {
    union { __hip_bfloat16 h; unsigned short u; } cv;
    cv.h = __float2bfloat16(f);                      // RNE
    return cv.u;
}

// Convert 8 consecutive f32 -> 8 bf16 and store 16B to LDS.
__device__ __forceinline__ void cvt8_store(unsigned short* dst, const float* src) {
    float4 f0 = *(const float4*)(src);
    float4 f1 = *(const float4*)(src + 4);
    unsigned short h[8];
    h[0] = f2bf(f0.x); h[1] = f2bf(f0.y); h[2] = f2bf(f0.z); h[3] = f2bf(f0.w);
    h[4] = f2bf(f1.x); h[5] = f2bf(f1.y); h[6] = f2bf(f1.z); h[7] = f2bf(f1.w);
    *(uint4*)dst = *(const uint4*)h;
}

// ---------------------------------------------------------------------------
// Kernel A: blockIdx.y in {0,1,2}: per-weight GEMM X@W^T (MFMA) + LIF over t,
// bit-packed spike output. blockIdx.y==3: rpb table expansion (folded in to
// kill one launch + overlap with QKV).
// ---------------------------------------------------------------------------
__global__ __launch_bounds__(256) void k_qkv_lif(
    const float* __restrict__ x,
    const float* __restrict__ Wq,
    const float* __restrict__ Wk,
    const float* __restrict__ Wv,
    const float* __restrict__ tbl,
    unsigned int* __restrict__ qbits,
    unsigned int* __restrict__ kbits,
    unsigned int* __restrict__ vbits,
    float* __restrict__ rpbx)
{
    if (blockIdx.y == 3) {
        // rpb expansion: 262144 elems / 256 blocks = 1024/block = 4/thread
        int base = blockIdx.x * 1024 + threadIdx.x * 4;
        int hh = base >> 16;
        int n = (base >> 8) & 255, m0 = base & 255;
        int zn = n >> 6, yn = (n >> 3) & 7, xn = n & 7;
        float4 o;
#pragma unroll
        for (int i = 0; i < 4; ++i) {
            int m = m0 + i;
            int zm = m >> 6, ym = (m >> 3) & 7, xm = m & 7;
            int ri = (zn - zm + 3) * 225 + (yn - ym + 7) * 15 + (xn - xm + 7);
            ((float*)&o)[i] = tbl[ri * 4 + hh];
        }
        *(float4*)&rpbx[base] = o;
        return;
    }

    __shared__ unsigned short Wl[128 * 136];   // W rows d (N) x cols c (K), pad +8
    __shared__ unsigned short Xl[64 * 136];    // X tile / spike tile (reused)

    const int tid = threadIdx.x;
    const int wv = tid >> 6, lane = tid & 63;
    const int l15 = lane & 15, lh = lane >> 4;
    const int wsel = blockIdx.y;
    const float* W = (wsel == 0) ? Wq : (wsel == 1) ? Wk : Wv;
    unsigned int* bits = (wsel == 0) ? qbits : (wsel == 1) ? kbits : vbits;
    const int B = blockIdx.x;

    {   // stage W (128x128 f32 -> bf16)
#pragma unroll
        for (int i = 0; i < 8; ++i) {
            int e = i * 2048 + tid * 8;
            int r = e >> 7, cc = e & 127;
            cvt8_store(&Wl[r * 136 + cc], W + r * 128 + cc);
        }
    }

    f32x4 vst[8];                                   // LIF membrane, persists over t
#pragma unroll
    for (int nt = 0; nt < 8; ++nt) vst[nt] = (f32x4){0.f, 0.f, 0.f, 0.f};

    for (int t = 0; t < 4; ++t) {
        __syncthreads();                            // Xl free (pack reads done)
        const float* xg = x + t * 2097152 + B * 8192;
#pragma unroll
        for (int i = 0; i < 4; ++i) {
            int e = i * 2048 + tid * 8;
            int r = e >> 7, cc = e & 127;
            cvt8_store(&Xl[r * 136 + cc], xg + r * 128 + cc);
        }
        __syncthreads();

        f32x4 acc[8];
#pragma unroll
        for (int nt = 0; nt < 8; ++nt) acc[nt] = (f32x4){0.f, 0.f, 0.f, 0.f};
#pragma unroll
        for (int kk = 0; kk < 4; ++kk) {
            bf16x8 a = *(const bf16x8*)&Xl[(wv * 16 + l15) * 136 + kk * 32 + lh * 8];
#pragma unroll
            for (int nt = 0; nt < 8; ++nt) {
                bf16x8 b = *(const bf16x8*)&Wl[(nt * 16 + l15) * 136 + kk * 32 + lh * 8];
                acc[nt] = MFMA16(a, b, acc[nt]);
            }
        }
        // LIF: v += (y-v)/2; s=(v>=1); v*=(1-s); spike shorts -> Xl
        unsigned short sp[8][4];
#pragma unroll
        for (int nt = 0; nt < 8; ++nt) {
#pragma unroll
            for (int reg = 0; reg < 4; ++reg) {
                float y = acc[nt][reg];
                float v = vst[nt][reg];
                v = v + (y - v) * 0.5f;
                float s = (v >= 1.0f) ? 1.0f : 0.0f;
                vst[nt][reg] = v * (1.0f - s);
                sp[nt][reg] = (s != 0.0f) ? (unsigned short)1 : (unsigned short)0;
            }
        }
        __syncthreads();                            // all MFMA reads of Xl done
#pragma unroll
        for (int nt = 0; nt < 8; ++nt)
#pragma unroll
            for (int reg = 0; reg < 4; ++reg)
                Xl[(wv * 16 + lh * 4 + reg) * 136 + nt * 16 + l15] = sp[nt][reg];
        __syncthreads();
        // pack: thread u owns n=u: row hw=u>>2, cols (u&3)*32 .. +31 -> 32 bits
        {
            const unsigned short* rowp = &Xl[(tid >> 2) * 136 + (tid & 3) * 32];
            unsigned int mask = 0;
#pragma unroll
            for (int j8 = 0; j8 < 4; ++j8) {
                uint4 u = *(const uint4*)(rowp + j8 * 8);
                int base = j8 * 8;
                if (u.x & 0xFFFFu) mask |= 1u << (base + 0);
                if (u.x >> 16)     mask |= 1u << (base + 1);
                if (u.y & 0xFFFFu) mask |= 1u << (base + 2);
                if (u.y >> 16)     mask |= 1u << (base + 3);
                if (u.z & 0xFFFFu) mask |= 1u << (base + 4);
                if (u.z >> 16)     mask |= 1u << (base + 5);
                if (u.w & 0xFFFFu) mask |= 1u << (base + 6);
                if (u.w >> 16)     mask |= 1u << (base + 7);
            }
            bits[(t * 256 + B) * 256 + tid] = mask;  // coalesced 1KB
        }
    }
}

// ---------------------------------------------------------------------------
// Kernel B: one block per group g=(b,head). attn[n][m] = popc(q&k)*SC + rpb,
// float4 nontemporal stores; bf16 copy in LDS; o = attn@v via MFMA.
// 32-row chunks -> LDS 34.8 KB -> 4 blocks/CU. PV MFMA: wave wv handles
// (row-tile rt = wv>>1, d-tile nh = wv&1) so all 4 waves are busy.
// ---------------------------------------------------------------------------
__global__ __launch_bounds__(256) void k_attn(
    const unsigned int* __restrict__ qbits,
    const unsigned int* __restrict__ kbits,
    const unsigned int* __restrict__ vbits,
    const float* __restrict__ rpbx,
    float* __restrict__ attn_out,
    unsigned short* __restrict__ o_ws)
{
    __shared__ unsigned int  qb[256];          // q row bitmasks
    __shared__ unsigned short vT[32 * 264];    // v transposed: [d][m], pad +8
    __shared__ unsigned short attnL[32 * 264]; // attn chunk bf16: [n_loc][m]

    const int tid = threadIdx.x;
    const int wv = tid >> 6, lane = tid & 63;
    const int l15 = lane & 15, lh = lane >> 4;
    const int g = blockIdx.x, hh = g & 3;

    qb[tid] = qbits[g * 256 + tid];
    uint4 km = *(const uint4*)&kbits[g * 256 + (tid & 63) * 4];
    {   // v bits -> bf16 vT[d][m]
        unsigned int vb = vbits[g * 256 + tid];
#pragma unroll
        for (int d = 0; d < 32; ++d)
            vT[d * 264 + tid] = ((vb >> d) & 1u) ? (unsigned short)0x3F80
                                                 : (unsigned short)0;
    }
    __syncthreads();

    const float SC = 0.17677669529663687f;     // 32^-0.5
    float* attn_b = attn_out + (size_t)g * 65536;
    const float* rp = rpbx + hh * 65536;
    unsigned short* ob = o_ws + g * 8192;
    const int rg = wv, m0 = (tid & 63) * 4;
    const int rt = wv >> 1, nh = wv & 1;       // PV work split

    for (int c = 0; c < 8; ++c) {              // 32-row chunks
        // rows n = c*32 + j*4 + rg; thread owns cols m0..m0+3
#pragma unroll
        for (int j = 0; j < 8; ++j) {
            int n = c * 32 + j * 4 + rg;
            unsigned int qn = qb[n];
            float4 rp4 = *(const float4*)&rp[n * 256 + m0];
            f32x4 av;
            av.x = (float)__popc(qn & km.x) * SC + rp4.x;
            av.y = (float)__popc(qn & km.y) * SC + rp4.y;
            av.z = (float)__popc(qn & km.z) * SC + rp4.z;
            av.w = (float)__popc(qn & km.w) * SC + rp4.w;
            __builtin_nontemporal_store(av, (f32x4*)(attn_b + n * 256 + m0));
            unsigned int p0 = (unsigned int)f2bf(av.x) | ((unsigned int)f2bf(av.y) << 16);
            unsigned int p1 = (unsigned int)f2bf(av.z) | ((unsigned int)f2bf(av.w) << 16);
            uint2 pk; pk.x = p0; pk.y = p1;
            *(uint2*)&attnL[(j * 4 + rg) * 264 + m0] = pk;
        }
        __syncthreads();
        // o(32x32) = attnL(32x256) @ v(256x32); wave (rt,nh) -> 16x16 tile
        f32x4 oc = (f32x4){0.f, 0.f, 0.f, 0.f};
#pragma unroll
        for (int kk = 0; kk < 8; ++kk) {
            bf16x8 a = *(const bf16x8*)&attnL[(rt * 16 + l15) * 264 + kk * 32 + lh * 8];
            bf16x8 b = *(const bf16x8*)&vT[(nh * 16 + l15) * 264 + kk * 32 + lh * 8];
            oc = MFMA16(a, b, oc);
        }
#pragma unroll
        for (int reg = 0; reg < 4; ++reg) {
            int n = c * 32 + rt * 16 + lh * 4 + reg;
            ob[n * 32 + nh * 16 + l15] = f2bf(oc[reg]);
        }
        __syncthreads();                        // attnL reuse next chunk
    }
}

// ---------------------------------------------------------------------------
// Kernel C: per b_new: gather o across heads -> A(256x128); Y = A@Wp^T + bias;
// LIF over t2 (rows n = t2*64 + hw). Chunked by hw (4 chunks of 16) so each
// wave holds all 4 timesteps of its elements in accumulators.
// ---------------------------------------------------------------------------
__global__ __launch_bounds__(256) void k_proj_lif(
    const unsigned short* __restrict__ o_ws,
    const float* __restrict__ Wp,
    const float* __restrict__ bp,
    float* __restrict__ out0)
{
    __shared__ unsigned short Wl[128 * 136];
    __shared__ unsigned short Al[64 * 136];

    const int tid = threadIdx.x;
    const int wv = tid >> 6, lane = tid & 63;
    const int l15 = lane & 15, lh = lane >> 4;
    const int b = blockIdx.x;

    {   // stage Wproj (f32 -> bf16)
#pragma unroll
        for (int i = 0; i < 8; ++i) {
            int e = i * 2048 + tid * 8;
            int r = e >> 7, cc = e & 127;
            cvt8_store(&Wl[r * 136 + cc], Wp + r * 128 + cc);
        }
    }

    float biasf[2];
#pragma unroll
    for (int ntl = 0; ntl < 2; ++ntl)
        biasf[ntl] = bp[(wv * 2 + ntl) * 16 + l15];

    const unsigned short* ob = o_ws + b * 32768;   // o[b][head][n][hd] bf16

    for (int c = 0; c < 4; ++c) {                  // hw group c*16 .. c*16+15
        __syncthreads();
        // Al rows lr2 = t2*16+rit, cols cc = head*32+hd; n = t2*64 + c*16 + rit
#pragma unroll
        for (int i = 0; i < 4; ++i) {
            int e = i * 2048 + tid * 8;
            int lr2 = e >> 7, cc = e & 127;
            int t2 = lr2 >> 4, rit = lr2 & 15;
            int hhh = cc >> 5, hd = cc & 31;
            int n = t2 * 64 + c * 16 + rit;
            *(uint4*)&Al[lr2 * 136 + cc] =
                *(const uint4*)(ob + (hhh * 256 + n) * 32 + hd);
        }
        __syncthreads();

        f32x4 acc[4][2];
#pragma unroll
        for (int t2 = 0; t2 < 4; ++t2)
#pragma unroll
            for (int ntl = 0; ntl < 2; ++ntl)
                acc[t2][ntl] = (f32x4){0.f, 0.f, 0.f, 0.f};
#pragma unroll
        for (int kk = 0; kk < 4; ++kk) {
            bf16x8 a[4];
#pragma unroll
            for (int t2 = 0; t2 < 4; ++t2)
                a[t2] = *(const bf16x8*)&Al[(t2 * 16 + l15) * 136 + kk * 32 + lh * 8];
#pragma unroll
            for (int ntl = 0; ntl < 2; ++ntl) {
                bf16x8 bb = *(const bf16x8*)&Wl[((wv * 2 + ntl) * 16 + l15) * 136 + kk * 32 + lh * 8];
#pragma unroll
                for (int t2 = 0; t2 < 4; ++t2)
                    acc[t2][ntl] = MFMA16(a[t2], bb, acc[t2][ntl]);
            }
        }
        // bias + LIF over t2, store spikes (f32 0/1, nontemporal)
#pragma unroll
        for (int ntl = 0; ntl < 2; ++ntl) {
            int d = (wv * 2 + ntl) * 16 + l15;
#pragma unroll
            for (int reg = 0; reg < 4; ++reg) {
                int hw = c * 16 + lh * 4 + reg;
                float v = 0.f;
#pragma unroll
                for (int t2 = 0; t2 < 4; ++t2) {
                    float y = acc[t2][ntl][reg] + biasf[ntl];
                    v = v + (y - v) * 0.5f;
                    float s = (v >= 1.0f) ? 1.0f : 0.0f;
                    v = v * (1.0f - s);
                    __builtin_nontemporal_store(
                        s, out0 + t2 * 2097152 + b * 8192 + hw * 128 + d);
                }
            }
        }
    }
}

// ---------------------------------------------------------------------------
extern "C" void kernel_launch(void* const* d_in, const int* in_sizes, int n_in,
                              void* d_out, int out_size, void* d_ws, size_t ws_size,
                              hipStream_t stream)
{
    const float* x   = (const float*)d_in[0];
    const float* Wq  = (const float*)d_in[1];
    const float* Wk  = (const float*)d_in[2];
    const float* Wv  = (const float*)d_in[3];
    const float* tbl = (const float*)d_in[4];
    const float* Wp  = (const float*)d_in[5];
    const float* bp  = (const float*)d_in[6];

    float* out0 = (float*)d_out;                                // 8388608 f32
    float* attn = out0 + 8388608;                               // 67108864 f32

    unsigned short* o_ws = (unsigned short*)d_ws;               // 8388608 bf16
    unsigned int* qbits = (unsigned int*)(o_ws + 8388608);      // 262144 u32
    unsigned int* kbits = qbits + 262144;
    unsigned int* vbits = kbits + 262144;
    float* rpbx = (float*)(vbits + 262144);                     // 262144 f32
    // total ws use: ~21 MB

    k_qkv_lif<<<dim3(256, 4), 256, 0, stream>>>(x, Wq, Wk, Wv, tbl,
                                                qbits, kbits, vbits, rpbx);
    k_attn<<<1024, 256, 0, stream>>>(qbits, kbits, vbits, rpbx, attn, o_ws);
    k_proj_lif<<<256, 256, 0, stream>>>(o_ws, Wp, bp, out0);
}